// Round 6
// baseline (32203.442 us; speedup 1.0000x reference)
//
#include <hip/hip_runtime.h>
#include <math.h>

// Boltzmann machine mean-field annealing on MI355X.
// field_h = [hid|vis](64x6144) @ W_h(6144x2048), field_v = [vis|hid] @ W_v(6144x4096)
// NUMERICS (locked by R1-R4 calibration): f16 hi/lo split on BOTH W and A
// (lo pre-scaled by 2^11), 3-term MFMA. Per-product rel err ~7e-7; dynamics
// amplify ~3000x, so anything coarser FAILS (bf16-split: 0.072, f16-W: 0.95).
// PERF: 64-col x K-split blocks (vis KSPLIT=4, hid KSPLIT=8) cut cross-block
// A redundancy 603->150 MB/pair. Cross-block K-reduce via last-arrival pattern
// (threadfence + device atomics, atomicExch self-reset). W loads non-temporal.
// R6 hardening vs R5: two-pass LDS reduce (34.8KB static LDS, <64KB), shared
// Pf buffer (ws footprint ~163MB), atomic-domain counter reset.

#define V_SIZE 4096
#define H_SIZE 2048
#define BATCH  64
#define K_TOT  6144
#define KT_TOT 192          // K_TOT / 32
#define STEPS  100
#define LO_SCALE 2048.0f    // 2^11
#define LO_INV   (1.0f / 2048.0f)

typedef _Float16 h16x8 __attribute__((ext_vector_type(8)));
typedef _Float16 h16x4 __attribute__((ext_vector_type(4)));
typedef float    f32x4 __attribute__((ext_vector_type(4)));

__device__ __forceinline__ void split_f16(float f, _Float16& hi, _Float16& lo) {
  hi = (_Float16)f;                       // RNE
  lo = (_Float16)((f - (float)hi) * LO_SCALE);
}

// Packed fragment layouts (same assumed slot->k map for A and B => any true HW
// permutation cancels in the dot):
//   A_pack[kt][mt][lane][slot]  (mt = batch-row/16)
//   W_pack[nt][kt][lane][slot]  (nt = out-col/16)   -> contiguous K-stream per nt
__device__ __forceinline__ size_t a_pack_off(int k, int b) {
  int kt = k >> 5;
  int g = (k >> 3) & 3;
  int lane = g * 16 + (b & 15);
  int mt = b >> 4;
  return ((size_t)(kt * 4 + mt) * 64 + lane) * 8;   // base of the 8-slot group
}

__device__ __forceinline__ f32x4 mfma16(h16x8 a, h16x8 b, f32x4 c) {
  return __builtin_amdgcn_mfma_f32_16x16x32_f16(a, b, c, 0, 0, 0);
}

// ---------------- weight pre-pack (once per launch) ----------------
__global__ void pack_W(const float* __restrict__ sym_raw, const float* __restrict__ vh,
                       _Float16* __restrict__ Whi, _Float16* __restrict__ Wlo,
                       int N, int mode) {
  int fid = blockIdx.x * 4 + (threadIdx.x >> 6);
  int lane = threadIdx.x & 63;
  int nt = fid / KT_TOT, kt = fid % KT_TOT;
  int j = nt * 16 + (lane & 15);
  int kbase = kt * 32 + ((lane >> 4) << 3);
  h16x8 hv, lv;
#pragma unroll
  for (int s = 0; s < 8; ++s) {
    int k = kbase + s;
    float wv;
    if (k < N) {
      wv = (k == j) ? 0.0f
         : (k < j ? sym_raw[(size_t)k * N + j] : sym_raw[(size_t)j * N + k]);
    } else {
      int r = k - N;
      wv = mode ? vh[(size_t)j * H_SIZE + r]    // W_v: vh^T
                : vh[(size_t)r * H_SIZE + j];   // W_h: vh
    }
    _Float16 h, l; split_f16(wv, h, l);
    hv[s] = h; lv[s] = l;
  }
  size_t off = ((size_t)fid * 64 + lane) * 8;
  *(h16x8*)(Whi + off) = hv;
  *(h16x8*)(Wlo + off) = lv;
}

// ---------------- state init ----------------
__global__ void init_state(const float* __restrict__ x,
                           float* __restrict__ vis_state, float* __restrict__ hid_state,
                           _Float16* __restrict__ Ah_hi, _Float16* __restrict__ Ah_lo,
                           _Float16* __restrict__ Av_hi, _Float16* __restrict__ Av_lo) {
  int idx = blockIdx.x * blockDim.x + threadIdx.x;
  if (idx < BATCH * (V_SIZE / 8)) {                       // vis: pack x
    int b = idx >> 9;
    int j0 = (idx & 511) * 8;
    h16x8 hv, lv;
#pragma unroll
    for (int jj = 0; jj < 8; ++jj) {
      float v = x[(size_t)b * V_SIZE + j0 + jj];
      vis_state[(size_t)b * V_SIZE + j0 + jj] = v;
      _Float16 h, l; split_f16(v, h, l);
      hv[jj] = h; lv[jj] = l;
    }
    size_t ov = a_pack_off(j0, b);                        // A_v rows [0,4096)
    *(h16x8*)(Av_hi + ov) = hv;  *(h16x8*)(Av_lo + ov) = lv;
    size_t oh = a_pack_off(H_SIZE + j0, b);               // A_h rows [2048,6144)
    *(h16x8*)(Ah_hi + oh) = hv;  *(h16x8*)(Ah_lo + oh) = lv;
  } else {                                                // hid: 0.5 (exact in f16)
    int t = idx - BATCH * (V_SIZE / 8);
    if (t < BATCH * (H_SIZE / 8)) {
      int b = t >> 8;
      int j0 = (t & 255) * 8;
      h16x8 hv, lv;
#pragma unroll
      for (int jj = 0; jj < 8; ++jj) {
        hid_state[(size_t)b * H_SIZE + j0 + jj] = 0.5f;
        hv[jj] = (_Float16)0.5f;
        lv[jj] = (_Float16)0.0f;
      }
      size_t o = a_pack_off(j0, b);                       // A_h rows [0,2048)
      *(h16x8*)(Ah_hi + o) = hv;  *(h16x8*)(Ah_lo + o) = lv;
    }
  }
}

// ---------------- fused GEMM + cross-block K-reduce + epilogue ----------------
// Block: 1024 thr = 16 waves. Owns 64 output cols (4 nt) x K/KSPLIT.
// Waves: ntl = w&3 (which nt), ksub = w>>2 (sub-K). grid = (N/64)*KSPLIT.
// Two-pass LDS reduce (waves 8-15 add into slices 0-7): 34.8KB static LDS.
// Last-arrival block per coltile sums KSPLIT partials, does sigmoid/blend/re-pack.
template <int N, int KSPLIT>
__launch_bounds__(1024, 4)
__global__ void gemm_step(const _Float16* __restrict__ Ahi, const _Float16* __restrict__ Alo,
                          const _Float16* __restrict__ Whi, const _Float16* __restrict__ Wlo,
                          const float* __restrict__ bias,
                          float* __restrict__ state,
                          float* __restrict__ Pf, int* __restrict__ cnt,
                          _Float16* __restrict__ dst1_hi, _Float16* __restrict__ dst1_lo, int rowoff1,
                          _Float16* __restrict__ dst2_hi, _Float16* __restrict__ dst2_lo, int rowoff2,
                          float invTemp) {
  constexpr int KTLOOP = KT_TOT / (KSPLIT * 4);   // 12 (K4) / 6 (K8)
  __shared__ float red[8][64][17];   // 34.8 KB
  __shared__ int isLast;
  const int ct = blockIdx.x / KSPLIT;
  const int ks = blockIdx.x % KSPLIT;
  const int tid = threadIdx.x;
  const int w = tid >> 6, lane = tid & 63;
  const int ntl = w & 3, ksub = w >> 2;
  const int nt = ct * 4 + ntl;
  const int kt0 = (ks * 4 + ksub) * KTLOOP;

  f32x4 accH[4] = {};
  f32x4 accL[4] = {};
  const _Float16* ahp = Ahi + (size_t)kt0 * 2048 + lane * 8;
  const _Float16* alp = Alo + (size_t)kt0 * 2048 + lane * 8;
  const h16x8* whp = (const h16x8*)(Whi + ((size_t)nt * KT_TOT + kt0) * 512 + lane * 8);
  const h16x8* wlp = (const h16x8*)(Wlo + ((size_t)nt * KT_TOT + kt0) * 512 + lane * 8);

#pragma unroll 2
  for (int kt = 0; kt < KTLOOP; ++kt) {
    h16x8 bh = __builtin_nontemporal_load(whp);   // nt: keep A resident in L2
    h16x8 bl = __builtin_nontemporal_load(wlp);
#pragma unroll
    for (int mt = 0; mt < 4; ++mt) {
      h16x8 xh = *(const h16x8*)(ahp + mt * 512);
      h16x8 xl = *(const h16x8*)(alp + mt * 512);
      accH[mt] = mfma16(xh, bh, accH[mt]);   // hi*hi
      accL[mt] = mfma16(xh, bl, accL[mt]);   // hi*lo'
      accL[mt] = mfma16(xl, bh, accL[mt]);   // lo'*hi
    }
    ahp += 2048; alp += 2048; whp += 64; wlp += 64;
  }

  // C/D layout (HW-verified): col = lane&15, row = (lane>>4)*4 + reg
  // Two-pass: waves 0-7 (ksub 0,1) write slice w; waves 8-15 (ksub 2,3) add into w-8.
  {
    const int col = lane & 15;
    const int r0 = (lane >> 4) << 2;
    if (w < 8) {
#pragma unroll
      for (int mt = 0; mt < 4; ++mt)
#pragma unroll
        for (int r = 0; r < 4; ++r)
          red[w][mt * 16 + r0 + r][col] = accH[mt][r] + accL[mt][r] * LO_INV;
    }
    __syncthreads();
    if (w >= 8) {
#pragma unroll
      for (int mt = 0; mt < 4; ++mt)
#pragma unroll
        for (int r = 0; r < 4; ++r)
          red[w - 8][mt * 16 + r0 + r][col] += accH[mt][r] + accL[mt][r] * LO_INV;
    }
  }
  __syncthreads();

  // partial field for (ct, ks): slices {ntl} + {ntl+4}; 64 b x 64 cols
  {
    int b = tid >> 4, j0 = (tid & 15) * 4;
    int jt = j0 >> 4;
    f32x4 v;
#pragma unroll
    for (int jj = 0; jj < 4; ++jj) {
      int jc = (j0 & 15) + jj;
      v[jj] = red[jt][b][jc] + red[4 + jt][b][jc];
    }
    *(f32x4*)(Pf + ((size_t)ks * 64 + b) * N + ct * 64 + j0) = v;
  }
  __threadfence();                 // release partials (device scope)
  if (tid == 0) {
    int old = atomicAdd(&cnt[ct], 1);
    isLast = (old == KSPLIT - 1);
    if (old == KSPLIT - 1) atomicExch(&cnt[ct], 0);   // atomic-domain self-reset
  }
  __syncthreads();
  if (!isLast) return;
  __threadfence();                 // acquire: see all blocks' partials

  // finish: sum KSPLIT partials, bias/sigmoid/blend, re-pack fragments
  {
    int b = tid >> 4, j0 = (tid & 15) * 4;
    int col0 = ct * 64 + j0;
    f32x4 f = *(const f32x4*)(bias + col0);
#pragma unroll
    for (int s = 0; s < KSPLIT; ++s) {
      f32x4 pv = *(const f32x4*)(Pf + ((size_t)s * 64 + b) * N + col0);
#pragma unroll
      for (int jj = 0; jj < 4; ++jj) f[jj] += pv[jj];
    }
    f32x4 st = *(const f32x4*)(state + (size_t)b * N + col0);
    h16x4 hv, lv;
#pragma unroll
    for (int jj = 0; jj < 4; ++jj) {
      float p = 1.0f / (1.0f + expf(-f[jj] * invTemp));
      float nv = 0.9f * st[jj] + 0.1f * p;
      st[jj] = nv;
      _Float16 h, l; split_f16(nv, h, l);
      hv[jj] = h; lv[jj] = l;
    }
    *(f32x4*)(state + (size_t)b * N + col0) = st;
    int k1 = rowoff1 + col0;
    size_t o1 = a_pack_off(k1, b) + (k1 & 7);
    *(h16x4*)(dst1_hi + o1) = hv;
    *(h16x4*)(dst1_lo + o1) = lv;
    int k2 = rowoff2 + col0;
    size_t o2 = a_pack_off(k2, b) + (k2 & 7);
    *(h16x4*)(dst2_hi + o2) = hv;
    *(h16x4*)(dst2_lo + o2) = lv;
  }
}

extern "C" void kernel_launch(void* const* d_in, const int* in_sizes, int n_in,
                              void* d_out, int out_size, void* d_ws, size_t ws_size,
                              hipStream_t stream) {
  const float* x        = (const float*)d_in[0];
  const float* vis_bias = (const float*)d_in[1];
  const float* hid_bias = (const float*)d_in[2];
  const float* vis_hid  = (const float*)d_in[3];
  const float* vv_raw   = (const float*)d_in[4];
  const float* hh_raw   = (const float*)d_in[5];

  char* ws = (char*)d_ws;
  auto alloc = [&](size_t bytes) {
    char* p = ws;
    ws += (bytes + 255) & ~(size_t)255;
    return p;
  };
  _Float16* Wh_hi = (_Float16*)alloc((size_t)K_TOT * H_SIZE * 2);
  _Float16* Wh_lo = (_Float16*)alloc((size_t)K_TOT * H_SIZE * 2);
  _Float16* Wv_hi = (_Float16*)alloc((size_t)K_TOT * V_SIZE * 2);
  _Float16* Wv_lo = (_Float16*)alloc((size_t)K_TOT * V_SIZE * 2);
  _Float16 *Ah_hi[2], *Ah_lo[2], *Av_hi[2], *Av_lo[2];
  for (int p = 0; p < 2; ++p) {
    Ah_hi[p] = (_Float16*)alloc((size_t)K_TOT * BATCH * 2);
    Ah_lo[p] = (_Float16*)alloc((size_t)K_TOT * BATCH * 2);
    Av_hi[p] = (_Float16*)alloc((size_t)K_TOT * BATCH * 2);
    Av_lo[p] = (_Float16*)alloc((size_t)K_TOT * BATCH * 2);
  }
  float* vis_state = (float*)alloc((size_t)BATCH * V_SIZE * 4);
  float* hid_state = (float*)alloc((size_t)BATCH * H_SIZE * 4);
  // Pf is produced+consumed within one dispatch -> vis and hid share one buffer.
  float* Pf = (float*)alloc((size_t)8 * BATCH * H_SIZE * 4);     // 4 MB (8*64*2048 == 4*64*4096)
  int* cnt_v = (int*)alloc((V_SIZE / 64) * sizeof(int));
  int* cnt_h = (int*)alloc((H_SIZE / 64) * sizeof(int));

  hipMemsetAsync(cnt_v, 0, (V_SIZE / 64) * sizeof(int), stream);
  hipMemsetAsync(cnt_h, 0, (H_SIZE / 64) * sizeof(int), stream);

  // one-time packs
  pack_W<<<(H_SIZE / 16) * KT_TOT / 4, 256, 0, stream>>>(hh_raw, vis_hid, Wh_hi, Wh_lo, H_SIZE, 0);
  pack_W<<<(V_SIZE / 16) * KT_TOT / 4, 256, 0, stream>>>(vv_raw, vis_hid, Wv_hi, Wv_lo, V_SIZE, 1);
  init_state<<<192, 256, 0, stream>>>(x, vis_state, hid_state,
                                      Ah_hi[0], Ah_lo[0], Av_hi[0], Av_lo[0]);

  for (int i = 0; i < STEPS; ++i) {
    float temp = 0.01f * (1.0f + 4.0f * expf(-5.0f * (float)i / (float)STEPS));
    float invT = 1.0f / temp;
    int p = i & 1, q = (i + 1) & 1;
    // hid update: reads A_h[p]; writes hid into A_h[q] rows [0,2048) and A_v[p] rows [4096,6144)
    gemm_step<H_SIZE, 8><<<(H_SIZE / 64) * 8, 1024, 0, stream>>>(
        Ah_hi[p], Ah_lo[p], Wh_hi, Wh_lo, hid_bias, hid_state,
        Pf, cnt_h,
        Ah_hi[q], Ah_lo[q], 0,
        Av_hi[p], Av_lo[p], V_SIZE, invT);
    // vis update: reads A_v[p]; writes vis into A_v[q] rows [0,4096) and A_h[q] rows [2048,6144)
    gemm_step<V_SIZE, 4><<<(V_SIZE / 64) * 4, 1024, 0, stream>>>(
        Av_hi[p], Av_lo[p], Wv_hi, Wv_lo, vis_bias, vis_state,
        Pf, cnt_v,
        Av_hi[q], Av_lo[q], 0,
        Ah_hi[q], Ah_lo[q], H_SIZE, invT);
  }
  hipMemcpyAsync(d_out, vis_state, (size_t)BATCH * V_SIZE * 4,
                 hipMemcpyDeviceToDevice, stream);
}

// Round 8
// 7103.034 us; speedup vs baseline: 4.5338x; 4.5338x over previous
//
#include <hip/hip_runtime.h>
#include <math.h>

// Boltzmann machine mean-field annealing on MI355X.
// field_h = [hid|vis](64x6144) @ W_h(6144x2048), field_v = [vis|hid] @ W_v(6144x4096)
// NUMERICS (locked by R1-R4 calibration): f16 hi/lo split on BOTH W and A
// (lo pre-scaled by 2^11), 3-term MFMA. Per-product rel err ~7e-7; dynamics
// amplify ~3000x, so anything coarser FAILS (bf16-split: 0.072, f16-W: 0.95).
// PERF (R7/R8): K-split blocks (vis KSPLIT=4, hid KSPLIT=8, 64 cols/block) cut
// cross-block A redundancy 603->150 MB/pair. Cross-block K-reduction happens
// ACROSS A KERNEL BOUNDARY (gemm writes partials with plain stores; tiny fin
// kernel sums+activates+repacks). NO in-kernel fences/atomics -- R6 showed
// per-wave __threadfence (L2 wbl2/inv on gfx950) serializes the whole GPU
// (179us/dispatch, all pipes idle). W loads non-temporal to keep A L2-resident.

#define V_SIZE 4096
#define H_SIZE 2048
#define BATCH  64
#define K_TOT  6144
#define KT_TOT 192          // K_TOT / 32
#define STEPS  100
#define LO_SCALE 2048.0f    // 2^11
#define LO_INV   (1.0f / 2048.0f)

typedef _Float16 h16x8 __attribute__((ext_vector_type(8)));
typedef _Float16 h16x4 __attribute__((ext_vector_type(4)));
typedef float    f32x4 __attribute__((ext_vector_type(4)));

__device__ __forceinline__ void split_f16(float f, _Float16& hi, _Float16& lo) {
  hi = (_Float16)f;                       // RNE
  lo = (_Float16)((f - (float)hi) * LO_SCALE);
}

// Packed fragment layouts (same assumed slot->k map for A and B => any true HW
// permutation cancels in the dot):
//   A_pack[kt][mt][lane][slot]  (mt = batch-row/16)
//   W_pack[nt][kt][lane][slot]  (nt = out-col/16)   -> contiguous K-stream per nt
__device__ __forceinline__ size_t a_pack_off(int k, int b) {
  int kt = k >> 5;
  int g = (k >> 3) & 3;
  int lane = g * 16 + (b & 15);
  int mt = b >> 4;
  return ((size_t)(kt * 4 + mt) * 64 + lane) * 8;   // base of the 8-slot group
}

__device__ __forceinline__ f32x4 mfma16(h16x8 a, h16x8 b, f32x4 c) {
  return __builtin_amdgcn_mfma_f32_16x16x32_f16(a, b, c, 0, 0, 0);
}

// ---------------- weight pre-pack (once per launch) ----------------
__global__ void pack_W(const float* __restrict__ sym_raw, const float* __restrict__ vh,
                       _Float16* __restrict__ Whi, _Float16* __restrict__ Wlo,
                       int N, int mode) {
  int fid = blockIdx.x * 4 + (threadIdx.x >> 6);
  int lane = threadIdx.x & 63;
  int nt = fid / KT_TOT, kt = fid % KT_TOT;
  int j = nt * 16 + (lane & 15);
  int kbase = kt * 32 + ((lane >> 4) << 3);
  h16x8 hv, lv;
#pragma unroll
  for (int s = 0; s < 8; ++s) {
    int k = kbase + s;
    float wv;
    if (k < N) {
      wv = (k == j) ? 0.0f
         : (k < j ? sym_raw[(size_t)k * N + j] : sym_raw[(size_t)j * N + k]);
    } else {
      int r = k - N;
      wv = mode ? vh[(size_t)j * H_SIZE + r]    // W_v: vh^T
                : vh[(size_t)r * H_SIZE + j];   // W_h: vh
    }
    _Float16 h, l; split_f16(wv, h, l);
    hv[s] = h; lv[s] = l;
  }
  size_t off = ((size_t)fid * 64 + lane) * 8;
  *(h16x8*)(Whi + off) = hv;
  *(h16x8*)(Wlo + off) = lv;
}

// ---------------- state init ----------------
__global__ void init_state(const float* __restrict__ x,
                           float* __restrict__ vis_state, float* __restrict__ hid_state,
                           _Float16* __restrict__ Ah_hi, _Float16* __restrict__ Ah_lo,
                           _Float16* __restrict__ Av_hi, _Float16* __restrict__ Av_lo) {
  int idx = blockIdx.x * blockDim.x + threadIdx.x;
  if (idx < BATCH * (V_SIZE / 8)) {                       // vis: pack x
    int b = idx >> 9;
    int j0 = (idx & 511) * 8;
    h16x8 hv, lv;
#pragma unroll
    for (int jj = 0; jj < 8; ++jj) {
      float v = x[(size_t)b * V_SIZE + j0 + jj];
      vis_state[(size_t)b * V_SIZE + j0 + jj] = v;
      _Float16 h, l; split_f16(v, h, l);
      hv[jj] = h; lv[jj] = l;
    }
    size_t ov = a_pack_off(j0, b);                        // A_v rows [0,4096)
    *(h16x8*)(Av_hi + ov) = hv;  *(h16x8*)(Av_lo + ov) = lv;
    size_t oh = a_pack_off(H_SIZE + j0, b);               // A_h rows [2048,6144)
    *(h16x8*)(Ah_hi + oh) = hv;  *(h16x8*)(Ah_lo + oh) = lv;
  } else {                                                // hid: 0.5 (exact in f16)
    int t = idx - BATCH * (V_SIZE / 8);
    if (t < BATCH * (H_SIZE / 8)) {
      int b = t >> 8;
      int j0 = (t & 255) * 8;
      h16x8 hv, lv;
#pragma unroll
      for (int jj = 0; jj < 8; ++jj) {
        hid_state[(size_t)b * H_SIZE + j0 + jj] = 0.5f;
        hv[jj] = (_Float16)0.5f;
        lv[jj] = (_Float16)0.0f;
      }
      size_t o = a_pack_off(j0, b);                       // A_h rows [0,2048)
      *(h16x8*)(Ah_hi + o) = hv;  *(h16x8*)(Ah_lo + o) = lv;
    }
  }
}

// ---------------- GEMM partial: 64 cols x K/KSPLIT per block ----------------
// Block: 1024 thr = 16 waves; ntl = w&3 (nt within coltile), ksub = w>>2.
// grid = (N/64)*KSPLIT. Two-pass LDS reduce -> Pf[ks][b][col] partial fields.
// NO fences, NO atomics: the fin kernel consumes across the dispatch boundary.
template <int N, int KSPLIT>
__launch_bounds__(1024, 4)
__global__ void gemm_step(const _Float16* __restrict__ Ahi, const _Float16* __restrict__ Alo,
                          const _Float16* __restrict__ Whi, const _Float16* __restrict__ Wlo,
                          float* __restrict__ Pf) {
  constexpr int KTLOOP = KT_TOT / (KSPLIT * 4);   // 12 (K4) / 6 (K8)
  __shared__ float red[8][64][17];   // 34.8 KB
  const int ct = blockIdx.x / KSPLIT;
  const int ks = blockIdx.x % KSPLIT;
  const int tid = threadIdx.x;
  const int w = tid >> 6, lane = tid & 63;
  const int ntl = w & 3, ksub = w >> 2;
  const int nt = ct * 4 + ntl;
  const int kt0 = (ks * 4 + ksub) * KTLOOP;

  f32x4 accH[4] = {};
  f32x4 accL[4] = {};
  const _Float16* ahp = Ahi + (size_t)kt0 * 2048 + lane * 8;
  const _Float16* alp = Alo + (size_t)kt0 * 2048 + lane * 8;
  const h16x8* whp = (const h16x8*)(Whi + ((size_t)nt * KT_TOT + kt0) * 512 + lane * 8);
  const h16x8* wlp = (const h16x8*)(Wlo + ((size_t)nt * KT_TOT + kt0) * 512 + lane * 8);

#pragma unroll 2
  for (int kt = 0; kt < KTLOOP; ++kt) {
    h16x8 bh = __builtin_nontemporal_load(whp);   // nt: keep A resident in L2
    h16x8 bl = __builtin_nontemporal_load(wlp);
#pragma unroll
    for (int mt = 0; mt < 4; ++mt) {
      h16x8 xh = *(const h16x8*)(ahp + mt * 512);
      h16x8 xl = *(const h16x8*)(alp + mt * 512);
      accH[mt] = mfma16(xh, bh, accH[mt]);   // hi*hi
      accL[mt] = mfma16(xh, bl, accL[mt]);   // hi*lo'
      accL[mt] = mfma16(xl, bh, accL[mt]);   // lo'*hi
    }
    ahp += 2048; alp += 2048; whp += 64; wlp += 64;
  }

  // C/D layout (HW-verified): col = lane&15, row = (lane>>4)*4 + reg
  // Two-pass: waves 0-7 write slice w; waves 8-15 add into slice w-8.
  {
    const int col = lane & 15;
    const int r0 = (lane >> 4) << 2;
    if (w < 8) {
#pragma unroll
      for (int mt = 0; mt < 4; ++mt)
#pragma unroll
        for (int r = 0; r < 4; ++r)
          red[w][mt * 16 + r0 + r][col] = accH[mt][r] + accL[mt][r] * LO_INV;
    }
    __syncthreads();
    if (w >= 8) {
#pragma unroll
      for (int mt = 0; mt < 4; ++mt)
#pragma unroll
        for (int r = 0; r < 4; ++r)
          red[w - 8][mt * 16 + r0 + r][col] += accH[mt][r] + accL[mt][r] * LO_INV;
    }
  }
  __syncthreads();

  // partial field for (ct, ks): slices {jt} + {jt+4}; 64 batch x 64 cols
  {
    int b = tid >> 4, j0 = (tid & 15) * 4;
    int jt = j0 >> 4;
    f32x4 v;
#pragma unroll
    for (int jj = 0; jj < 4; ++jj) {
      int jc = (j0 & 15) + jj;
      v[jj] = red[jt][b][jc] + red[4 + jt][b][jc];
    }
    *(f32x4*)(Pf + ((size_t)ks * 64 + b) * N + ct * 64 + j0) = v;
  }
}

// ---------------- fin: sum partials + bias/sigmoid/blend + re-pack ----------------
// Thread -> (b, 4 cols). grid = BATCH*N/4096 blocks of 1024.
template <int N, int KSPLIT>
__launch_bounds__(1024)
__global__ void fin_step(const float* __restrict__ Pf, const float* __restrict__ bias,
                         float* __restrict__ state,
                         _Float16* __restrict__ dst1_hi, _Float16* __restrict__ dst1_lo, int rowoff1,
                         _Float16* __restrict__ dst2_hi, _Float16* __restrict__ dst2_lo, int rowoff2,
                         float invTemp) {
  int idx = blockIdx.x * 1024 + threadIdx.x;
  int b = idx / (N / 4);
  int col0 = (idx % (N / 4)) * 4;

  f32x4 f = *(const f32x4*)(bias + col0);
#pragma unroll
  for (int s = 0; s < KSPLIT; ++s) {
    f32x4 pv = *(const f32x4*)(Pf + ((size_t)s * 64 + b) * N + col0);
#pragma unroll
    for (int jj = 0; jj < 4; ++jj) f[jj] += pv[jj];
  }
  f32x4 st = *(const f32x4*)(state + (size_t)b * N + col0);
  h16x4 hv, lv;
#pragma unroll
  for (int jj = 0; jj < 4; ++jj) {
    float p = 1.0f / (1.0f + expf(-f[jj] * invTemp));
    float nv = 0.9f * st[jj] + 0.1f * p;
    st[jj] = nv;
    _Float16 h, l; split_f16(nv, h, l);
    hv[jj] = h; lv[jj] = l;
  }
  *(f32x4*)(state + (size_t)b * N + col0) = st;
  int k1 = rowoff1 + col0;
  size_t o1 = a_pack_off(k1, b) + (k1 & 7);
  *(h16x4*)(dst1_hi + o1) = hv;
  *(h16x4*)(dst1_lo + o1) = lv;
  int k2 = rowoff2 + col0;
  size_t o2 = a_pack_off(k2, b) + (k2 & 7);
  *(h16x4*)(dst2_hi + o2) = hv;
  *(h16x4*)(dst2_lo + o2) = lv;
}

extern "C" void kernel_launch(void* const* d_in, const int* in_sizes, int n_in,
                              void* d_out, int out_size, void* d_ws, size_t ws_size,
                              hipStream_t stream) {
  const float* x        = (const float*)d_in[0];
  const float* vis_bias = (const float*)d_in[1];
  const float* hid_bias = (const float*)d_in[2];
  const float* vis_hid  = (const float*)d_in[3];
  const float* vv_raw   = (const float*)d_in[4];
  const float* hh_raw   = (const float*)d_in[5];

  char* ws = (char*)d_ws;
  auto alloc = [&](size_t bytes) {
    char* p = ws;
    ws += (bytes + 255) & ~(size_t)255;
    return p;
  };
  _Float16* Wh_hi = (_Float16*)alloc((size_t)K_TOT * H_SIZE * 2);
  _Float16* Wh_lo = (_Float16*)alloc((size_t)K_TOT * H_SIZE * 2);
  _Float16* Wv_hi = (_Float16*)alloc((size_t)K_TOT * V_SIZE * 2);
  _Float16* Wv_lo = (_Float16*)alloc((size_t)K_TOT * V_SIZE * 2);
  _Float16 *Ah_hi[2], *Ah_lo[2], *Av_hi[2], *Av_lo[2];
  for (int p = 0; p < 2; ++p) {
    Ah_hi[p] = (_Float16*)alloc((size_t)K_TOT * BATCH * 2);
    Ah_lo[p] = (_Float16*)alloc((size_t)K_TOT * BATCH * 2);
    Av_hi[p] = (_Float16*)alloc((size_t)K_TOT * BATCH * 2);
    Av_lo[p] = (_Float16*)alloc((size_t)K_TOT * BATCH * 2);
  }
  float* vis_state = (float*)alloc((size_t)BATCH * V_SIZE * 4);
  float* hid_state = (float*)alloc((size_t)BATCH * H_SIZE * 4);
  // Pf produced+consumed within one step phase -> vis and hid share one buffer.
  float* Pf = (float*)alloc((size_t)8 * BATCH * H_SIZE * 4);     // 4 MB

  // one-time packs
  pack_W<<<(H_SIZE / 16) * KT_TOT / 4, 256, 0, stream>>>(hh_raw, vis_hid, Wh_hi, Wh_lo, H_SIZE, 0);
  pack_W<<<(V_SIZE / 16) * KT_TOT / 4, 256, 0, stream>>>(vv_raw, vis_hid, Wv_hi, Wv_lo, V_SIZE, 1);
  init_state<<<192, 256, 0, stream>>>(x, vis_state, hid_state,
                                      Ah_hi[0], Ah_lo[0], Av_hi[0], Av_lo[0]);

  for (int i = 0; i < STEPS; ++i) {
    float temp = 0.01f * (1.0f + 4.0f * expf(-5.0f * (float)i / (float)STEPS));
    float invT = 1.0f / temp;
    int p = i & 1, q = (i + 1) & 1;
    // hid update: reads A_h[p]; fin writes hid into A_h[q] rows [0,2048)
    // and A_v[p] rows [4096,6144)
    gemm_step<H_SIZE, 8><<<(H_SIZE / 64) * 8, 1024, 0, stream>>>(
        Ah_hi[p], Ah_lo[p], Wh_hi, Wh_lo, Pf);
    fin_step<H_SIZE, 8><<<BATCH * H_SIZE / 4096, 1024, 0, stream>>>(
        Pf, hid_bias, hid_state,
        Ah_hi[q], Ah_lo[q], 0,
        Av_hi[p], Av_lo[p], V_SIZE, invT);
    // vis update: reads A_v[p]; fin writes vis into A_v[q] rows [0,4096)
    // and A_h[q] rows [2048,6144)
    gemm_step<V_SIZE, 4><<<(V_SIZE / 64) * 4, 1024, 0, stream>>>(
        Av_hi[p], Av_lo[p], Wv_hi, Wv_lo, Pf);
    fin_step<V_SIZE, 4><<<BATCH * V_SIZE / 4096, 1024, 0, stream>>>(
        Pf, vis_bias, vis_state,
        Av_hi[q], Av_lo[q], 0,
        Ah_hi[q], Ah_lo[q], H_SIZE, invT);
  }
  hipMemcpyAsync(d_out, vis_state, (size_t)BATCH * V_SIZE * 4,
                 hipMemcpyDeviceToDevice, stream);
}